// Round 9
// baseline (277.171 us; speedup 1.0000x reference)
//
#include <hip/hip_runtime.h>

// InstantNGP hash-grid forward, fp32 — dx-pair-per-lane layout.
//
// 4 lanes per (point, level): lane owns a (dy,dz) corner pair, loads both dx
// corners (rows b and b+1 — same 64B line 75% when adjacent). One wave = one
// point (64 lanes = 16 levels × 4), so the 3 coord loads are a single
// same-address broadcast set per wave (3 lines/pt, was 6), and the redundant
// weight math drops from 8x to 4x. Corner-pair sums reduce via 2-step
// shfl_xor butterfly; lane (tid&3)==0 stores the float4 (wave store = 256B).
//
// Level constants (verified vs reference _level_consts(), HW-validated
// R4/R6/R7/R8): res = 16<<l ; mask = (1<<min(12+3l,19))-1
//   l 0-2  : linear, strides [1, res, res^2]
//   l 3-11 : hash (primes 1, 2654435761, 805459861)
//   l 12-15: linear, strides [1, res, 0]  (uint32 wrap; l15: y*2^19 & mask = 0
//            -> duplicate slots dedup via wave same-address broadcast)
//
// Bottleneck model (5-config fit): dur = distinct-64B-lines/pt × ~3.2 cy/CU,
// invariant to residency (R2), HBM traffic (R4), L1 bypass (R7), scalar
// coords (R8). This round: 92 -> ~89 lines/pt, predicted ~250 µs. Hash-level
// gathers (58.5 lines/pt) are the irreducible core.

static constexpr int N_PTS = 500000;

typedef float f4 __attribute__((ext_vector_type(4)));

__global__ __launch_bounds__(256) void hashgrid_fwd(
    const float* __restrict__ coords,   // [N,3]
    const float* __restrict__ table,    // [T,4]
    float* __restrict__ out)            // [N,64]
{
    const unsigned tid = threadIdx.x;
    const unsigned wv = tid >> 6;         // wave in block = local point (0..3)
    const unsigned l = (tid >> 2) & 15u;  // level
    const unsigned q = tid & 3u;          // (dy,dz) pair index
    const unsigned dy = q & 1u;
    const unsigned dz = q >> 1;

    const unsigned n = blockIdx.x * 4u + wv;

    // whole wave shares one point -> 3 same-address broadcast loads
    const float cx = coords[(size_t)n * 3u + 0u];
    const float cy = coords[(size_t)n * 3u + 1u];
    const float cz = coords[(size_t)n * 3u + 2u];

    const unsigned res = 16u << l;
    const float scale = (float)(res - 1u);

    // pos = c*scale + 0.5, no fma contraction (match np fp32 floor boundaries)
    const float px = __fadd_rn(__fmul_rn(cx, scale), 0.5f);
    const float py = __fadd_rn(__fmul_rn(cy, scale), 0.5f);
    const float pz = __fadd_rn(__fmul_rn(cz, scale), 0.5f);
    const float bxf = floorf(px), byf = floorf(py), bzf = floorf(pz);
    const float fx = __fsub_rn(px, bxf);
    const float fy = __fsub_rn(py, byf);
    const float fz = __fsub_rn(pz, bzf);
    const unsigned x = (unsigned)(int)bxf;
    const unsigned y = (unsigned)(int)byf + dy;
    const unsigned z = (unsigned)(int)bzf + dz;

    const unsigned mask = (l >= 3u) ? 0x7FFFFu : ((1u << (12u + 3u * l)) - 1u);

    // weights for the two dx corners of this lane's (dy,dz)
    const float wy = dy ? fy : (1.0f - fy);
    const float wz = dz ? fz : (1.0f - fz);
    const float wyz = wy * wz;
    const float w0 = (1.0f - fx) * wyz;   // dx = 0
    const float w1 = fx * wyz;            // dx = 1

    unsigned slot0, slot1;
    if (l >= 3u && l < 12u) {           // hash levels
        const unsigned h = (y * 2654435761u) ^ (z * 805459861u);
        slot0 = (x ^ h) & mask;
        slot1 = ((x + 1u) ^ h) & mask;
    } else {                            // linear levels
        const unsigned zs = (l < 3u) ? res * res : 0u;   // l>=12: z-stride 0
        const unsigned b = x + y * res + z * zs;         // uint32 wrap = ref
        slot0 = (b) & mask;
        slot1 = (b + 1u) & mask;
    }

    const f4 e0 = *(const f4*)(table + (size_t)slot0 * 4u);
    const f4 e1 = *(const f4*)(table + (size_t)slot1 * 4u);
    float r0 = fmaf(w0, e0.x, w1 * e1.x);
    float r1 = fmaf(w0, e0.y, w1 * e1.y);
    float r2 = fmaf(w0, e0.z, w1 * e1.z);
    float r3 = fmaf(w0, e0.w, w1 * e1.w);

    // butterfly reduce over the 4 (dy,dz) lanes
    #pragma unroll
    for (int m = 1; m <= 2; m <<= 1) {
        r0 += __shfl_xor(r0, m, 64);
        r1 += __shfl_xor(r1, m, 64);
        r2 += __shfl_xor(r2, m, 64);
        r3 += __shfl_xor(r3, m, 64);
    }

    if (q == 0u) {
        f4 o; o.x = r0; o.y = r1; o.z = r2; o.w = r3;
        __builtin_nontemporal_store(o, (f4*)(out + (size_t)n * 64u + (size_t)l * 4u));
    }
}

extern "C" void kernel_launch(void* const* d_in, const int* in_sizes, int n_in,
                              void* d_out, int out_size, void* d_ws, size_t ws_size,
                              hipStream_t stream) {
    const float* coords = (const float*)d_in[0];
    const float* table  = (const float*)d_in[1];
    float* out = (float*)d_out;

    const int blocks = N_PTS / 4;   // 4 points per 256-thread block (1/wave)
    hipLaunchKernelGGL(hashgrid_fwd, dim3(blocks), dim3(256), 0, stream,
                       coords, table, out);
}

// Round 10
// 259.201 us; speedup vs baseline: 1.0693x; 1.0693x over previous
//
#include <hip/hip_runtime.h>

// InstantNGP hash-grid forward, fp32 — corner-per-lane layout (R6, best: 259 µs).
//
// FINAL STRUCTURE after 9 rounds of probes. 8 lanes per (point, level), one
// corner per lane, dx = lane bit 0 so dx-pairs coalesce to one 64B line on
// linear levels (and 37.5% of hash gathers); duplicate slots at l>=12
// (z-stride wrapped to 0 by uint32 overflow; l15's y*2^19 vanishes under
// &mask) dedup via the wave same-address broadcast path. 8-lane shfl_xor
// butterfly reduces corners; lane c==0 stores the float4 (contiguous 256B
// per wave).
//
// Level constants (verified vs reference _level_consts(), HW-validated):
//   res = 16<<l ; mask = (1<<min(12+3l,19))-1
//   l 0-2  : linear, strides [1, res, res^2]
//   l 3-11 : hash (primes 1, 2654435761, 805459861)
//   l 12-15: linear, strides [1, res, 0]
//
// Bottleneck (established R1-R9): per-CU gather-request processing at
// ~3.0 cy per unique 64B line, INVARIANT to: L2 residency (R2 split: FETCH
// 919->58 MB, dur unchanged), HBM traffic (R4), L1 bypass via sc0 (R7 A/B:
// exactly neutral), scalar-path coords (R8), waves-per-point shape (R9:
// fewer requests but less TA over-subscription -> slower). The ~72/pt random
// hash gathers (l3-11) are algorithmically irreducible with uniform-random
// coords. This kernel sits ~10% above the idealized request-count floor,
// inside the model's own scatter. Request-path roofline.

static constexpr int N_PTS = 500000;

typedef float f4 __attribute__((ext_vector_type(4)));

__global__ __launch_bounds__(256) void hashgrid_fwd(
    const float* __restrict__ coords,   // [N,3]
    const float* __restrict__ table,    // [T,4]
    float* __restrict__ out)            // [N,64]
{
    const unsigned tid = threadIdx.x;
    const unsigned p = tid >> 7;          // local point (0..1)
    const unsigned l = (tid >> 3) & 15u;  // level
    const unsigned c = tid & 7u;          // corner
    const unsigned dx = c & 1u;
    const unsigned dy = (c >> 1) & 1u;
    const unsigned dz = c >> 2;

    const unsigned n = blockIdx.x * 2u + p;

    const float cx = coords[(size_t)n * 3u + 0u];
    const float cy = coords[(size_t)n * 3u + 1u];
    const float cz = coords[(size_t)n * 3u + 2u];

    const unsigned res = 16u << l;
    const float scale = (float)(res - 1u);

    // pos = c*scale + 0.5, no fma contraction (match np fp32 floor boundaries)
    const float px = __fadd_rn(__fmul_rn(cx, scale), 0.5f);
    const float py = __fadd_rn(__fmul_rn(cy, scale), 0.5f);
    const float pz = __fadd_rn(__fmul_rn(cz, scale), 0.5f);
    const float bxf = floorf(px), byf = floorf(py), bzf = floorf(pz);
    const float fx = __fsub_rn(px, bxf);
    const float fy = __fsub_rn(py, byf);
    const float fz = __fsub_rn(pz, bzf);
    const unsigned x = (unsigned)(int)bxf + dx;
    const unsigned y = (unsigned)(int)byf + dy;
    const unsigned z = (unsigned)(int)bzf + dz;

    const unsigned mask = (l >= 3u) ? 0x7FFFFu : ((1u << (12u + 3u * l)) - 1u);

    // this lane's trilinear weight, product order matches np.prod (x*y*z)
    const float wx = dx ? fx : (1.0f - fx);
    const float wy = dy ? fy : (1.0f - fy);
    const float wz = dz ? fz : (1.0f - fz);
    const float w = wx * wy * wz;

    unsigned slot;
    if (l >= 3u && l < 12u) {           // hash levels
        slot = (x ^ (y * 2654435761u) ^ (z * 805459861u)) & mask;
    } else {                            // linear levels
        const unsigned zs = (l < 3u) ? res * res : 0u;   // l>=12: z-stride 0
        slot = (x + y * res + z * zs) & mask;            // uint32 wrap = ref
    }

    const f4 e = *(const f4*)(table + (size_t)slot * 4u);
    float r0 = w * e.x;
    float r1 = w * e.y;
    float r2 = w * e.z;
    float r3 = w * e.w;

    // butterfly reduce over the 8 corner lanes
    #pragma unroll
    for (int m = 1; m <= 4; m <<= 1) {
        r0 += __shfl_xor(r0, m, 64);
        r1 += __shfl_xor(r1, m, 64);
        r2 += __shfl_xor(r2, m, 64);
        r3 += __shfl_xor(r3, m, 64);
    }

    if (c == 0u) {
        f4 o; o.x = r0; o.y = r1; o.z = r2; o.w = r3;
        __builtin_nontemporal_store(o, (f4*)(out + (size_t)n * 64u + (size_t)l * 4u));
    }
}

extern "C" void kernel_launch(void* const* d_in, const int* in_sizes, int n_in,
                              void* d_out, int out_size, void* d_ws, size_t ws_size,
                              hipStream_t stream) {
    const float* coords = (const float*)d_in[0];
    const float* table  = (const float*)d_in[1];
    float* out = (float*)d_out;

    const int blocks = N_PTS / 2;   // 2 points per 256-thread block
    hipLaunchKernelGGL(hashgrid_fwd, dim3(blocks), dim3(256), 0, stream,
                       coords, table, out);
}